// Round 11
// baseline (532.619 us; speedup 1.0000x reference)
//
#include <hip/hip_runtime.h>
#include <hip/hip_bf16.h>

#define NN 50000
#define EE 800000
#define ELN 100000
#define ETOT (EE + NN)
#define NT 311
#define SCAN_B ((NN + 255) / 256)   // 196

typedef _Float16 f16;
typedef f16 f16x8 __attribute__((ext_vector_type(8)));
typedef f16 f16x4 __attribute__((ext_vector_type(4)));
typedef f16 f16x2 __attribute__((ext_vector_type(2)));
typedef float f32x4 __attribute__((ext_vector_type(4)));

// ---------------- prep: node types + x_comb [N,64] f16 (zero-padded 48->64) ----------------
__global__ __launch_bounds__(256) void k_prep(const float* __restrict__ x,
                                              const float* __restrict__ emb,
                                              f16* __restrict__ xc,
                                              int* __restrict__ ntypes)
{
    int n = blockIdx.x * 256 + threadIdx.x;
    if (n >= NN) return;
    int tpe = (int)x[(size_t)n * 33];
    tpe = tpe < 0 ? 0 : (tpe > NT - 1 ? NT - 1 : tpe);
    ntypes[n] = tpe;
    f16* o = xc + (size_t)n * 64;
    #pragma unroll
    for (int j = 0; j < 16; ++j) o[j] = (f16)emb[tpe * 16 + j];
    #pragma unroll
    for (int j = 0; j < 32; ++j) o[16 + j] = (f16)x[(size_t)n * 33 + 1 + j];
    #pragma unroll
    for (int j = 48; j < 64; ++j) o[j] = (f16)0.f;
}

// ---------------- weight convert+transpose: W[K][CN] f32 -> Wt[CN][KP] f16 ----------------
template<int K, int KP, int CN>
__global__ __launch_bounds__(256) void k_cvtw(const float* __restrict__ W,
                                              f16* __restrict__ Wt)
{
    int idx = blockIdx.x * 256 + threadIdx.x;
    if (idx >= CN * KP) return;
    int c = idx / KP;
    int k = idx - c * KP;
    Wt[idx] = (k < K) ? (f16)W[(size_t)k * CN + c] : (f16)0.f;
}

// ---- W1 per-head transpose ----
__global__ __launch_bounds__(256) void k_cvtw1(const float* __restrict__ W1,
                                               f16* __restrict__ Wt1)
{
    int idx = blockIdx.x * 256 + threadIdx.x;
    if (idx >= 4 * 64 * 64) return;
    int h = idx >> 12;
    int c = (idx >> 6) & 63;
    int k = idx & 63;
    Wt1[idx] = (k < 48) ? (f16)W1[(size_t)k * 256 + h * 64 + c] : (f16)0.f;
}

// ---- fold a_src/a_dst through W1 ----
__global__ __launch_bounds__(256) void k_pre1(const float* __restrict__ W1,
                                              const float* __restrict__ as1,
                                              const float* __restrict__ ad1,
                                              float* __restrict__ a1ps,
                                              float* __restrict__ a1pd)
{
    int t = threadIdx.x;
    int h = t >> 6, k = t & 63;
    float ss = 0.f, sd = 0.f;
    if (k < 48) {
        for (int d = 0; d < 64; ++d) {
            float w = W1[(size_t)k * 256 + h * 64 + d];
            ss += w * as1[h * 64 + d];
            sd += w * ad1[h * 64 + d];
        }
    }
    a1ps[t] = ss;
    a1pd[t] = sd;
}

// ---------------- CSR build ----------------
__global__ __launch_bounds__(256) void k_deg(const int* __restrict__ ei,
                                             int* __restrict__ counts)
{
    int e = blockIdx.x * 256 + threadIdx.x;
    if (e >= ETOT) return;
    int dst = (e < EE) ? ei[EE + e] : (e - EE);
    atomicAdd(&counts[dst], 1);
}

// ---- 3-phase scan ----
__global__ __launch_bounds__(256) void k_scan1(const int* __restrict__ counts,
                                               int* __restrict__ rowptr,
                                               int* __restrict__ blocksums)
{
    __shared__ int s[256];
    int t = threadIdx.x;
    int i = blockIdx.x * 256 + t;
    int v = (i < NN) ? counts[i] : 0;
    s[t] = v;
    __syncthreads();
    #pragma unroll
    for (int off = 1; off < 256; off <<= 1) {
        int u = (t >= off) ? s[t - off] : 0;
        __syncthreads();
        s[t] += u;
        __syncthreads();
    }
    int incl = s[t];
    if (i < NN) rowptr[i] = incl - v;
    if (t == 255) blocksums[blockIdx.x] = incl;
}

__global__ __launch_bounds__(256) void k_scan2(int* __restrict__ blocksums,
                                               int* __restrict__ blockoff)
{
    __shared__ int s[256];
    int t = threadIdx.x;
    int v = (t < SCAN_B) ? blocksums[t] : 0;
    s[t] = v;
    __syncthreads();
    #pragma unroll
    for (int off = 1; off < 256; off <<= 1) {
        int u = (t >= off) ? s[t - off] : 0;
        __syncthreads();
        s[t] += u;
        __syncthreads();
    }
    if (t < SCAN_B) blockoff[t] = s[t] - v;
    if (t == SCAN_B - 1) blockoff[SCAN_B] = s[t];
}

__global__ __launch_bounds__(256) void k_scan3(int* __restrict__ rowptr,
                                               const int* __restrict__ blockoff,
                                               int* __restrict__ cursor)
{
    int i = blockIdx.x * 256 + threadIdx.x;
    if (i < NN) {
        int v = rowptr[i] + blockoff[blockIdx.x];
        rowptr[i] = v;
        cursor[i] = v;
    }
    if (i == 0) rowptr[NN] = blockoff[SCAN_B];
}

__global__ __launch_bounds__(256) void k_fill(const int* __restrict__ ei,
                                              int* __restrict__ cursor,
                                              int* __restrict__ csr_src)
{
    int e = blockIdx.x * 256 + threadIdx.x;
    if (e >= ETOT) return;
    int src, dst;
    if (e < EE) { src = ei[e]; dst = ei[EE + e]; }
    else        { src = e - EE; dst = e - EE; }
    int pos = atomicAdd(&cursor[dst], 1);
    csr_src[pos] = src;
}

// ---- dense dstarr fill: slots of node n are [rowptr[n], rowptr[n+1]) ----
__global__ __launch_bounds__(256) void k_dfill(const int* __restrict__ rowptr,
                                               int* __restrict__ dstarr)
{
    int n = blockIdx.x * 256 + threadIdx.x;
    if (n >= NN) return;
    int r0 = rowptr[n], r1 = rowptr[n + 1];
    for (int i = r0; i < r1; ++i) dstarr[i] = n;
}

// ------------- MFMA f16 GEMM -------------
template<int K, int CN>
__global__ __launch_bounds__(256) void k_gemmh(const f16* __restrict__ A,
                                               const f16* __restrict__ Wt,
                                               f16* __restrict__ O,
                                               int nrows)
{
    constexpr int LDA = 40;
    __shared__ f16 As[64 * LDA];
    __shared__ f16 Bs[64 * LDA];
    const int t = threadIdx.x;
    const int w = t >> 6;
    const int lane = t & 63;
    const int m = lane & 15;
    const int quad = lane >> 4;
    const int row0 = blockIdx.x * 64;
    const int col0 = blockIdx.y * 64;
    const int r_st = t >> 2;
    const int seg  = (t & 3) * 8;
    f32x4 acc[4] = {{0.f,0.f,0.f,0.f},{0.f,0.f,0.f,0.f},{0.f,0.f,0.f,0.f},{0.f,0.f,0.f,0.f}};
    for (int k0 = 0; k0 < K; k0 += 32) {
        int gr = row0 + r_st;
        f16x8 av = {0,0,0,0,0,0,0,0};
        if (gr < nrows) av = *(const f16x8*)&A[(size_t)gr * K + k0 + seg];
        *(f16x8*)&As[r_st * LDA + seg] = av;
        f16x8 bv = *(const f16x8*)&Wt[(size_t)(col0 + r_st) * K + k0 + seg];
        *(f16x8*)&Bs[r_st * LDA + seg] = bv;
        __syncthreads();
        f16x8 af = *(const f16x8*)&As[(w * 16 + m) * LDA + quad * 8];
        #pragma unroll
        for (int g = 0; g < 4; ++g) {
            f16x8 bf = *(const f16x8*)&Bs[(g * 16 + m) * LDA + quad * 8];
            acc[g] = __builtin_amdgcn_mfma_f32_16x16x32_f16(af, bf, acc[g], 0, 0, 0);
        }
        __syncthreads();
    }
    #pragma unroll
    for (int g = 0; g < 4; ++g) {
        #pragma unroll
        for (int reg = 0; reg < 4; ++reg) {
            int gr = row0 + w * 16 + quad * 4 + reg;
            int gc = col0 + g * 16 + m;
            if (gr < nrows) O[(size_t)gr * CN + gc] = (f16)acc[g][reg];
        }
    }
}

// ----- layer-1 per-head GEMM with fused bias+ELU -----
__global__ __launch_bounds__(256) void k_gemm1h(const f16* __restrict__ A,
                                                const f16* __restrict__ Wt1,
                                                const float* __restrict__ bias,
                                                f16* __restrict__ O,
                                                int nrows)
{
    constexpr int LDA = 40;
    __shared__ f16 As[64 * LDA];
    __shared__ f16 Bs[64 * LDA];
    const int t = threadIdx.x;
    const int w = t >> 6;
    const int lane = t & 63;
    const int m = lane & 15;
    const int quad = lane >> 4;
    const int row0 = blockIdx.x * 64;
    const int head = blockIdx.y;
    const int r_st = t >> 2;
    const int seg  = (t & 3) * 8;
    f32x4 acc[4] = {{0.f,0.f,0.f,0.f},{0.f,0.f,0.f,0.f},{0.f,0.f,0.f,0.f},{0.f,0.f,0.f,0.f}};
    for (int k0 = 0; k0 < 64; k0 += 32) {
        int gr = row0 + r_st;
        f16x8 av = {0,0,0,0,0,0,0,0};
        if (gr < nrows) av = *(const f16x8*)&A[(size_t)gr * 256 + head * 64 + k0 + seg];
        *(f16x8*)&As[r_st * LDA + seg] = av;
        f16x8 bv = *(const f16x8*)&Wt1[(size_t)head * 4096 + (size_t)r_st * 64 + k0 + seg];
        *(f16x8*)&Bs[r_st * LDA + seg] = bv;
        __syncthreads();
        f16x8 af = *(const f16x8*)&As[(w * 16 + m) * LDA + quad * 8];
        #pragma unroll
        for (int g = 0; g < 4; ++g) {
            f16x8 bf = *(const f16x8*)&Bs[(g * 16 + m) * LDA + quad * 8];
            acc[g] = __builtin_amdgcn_mfma_f32_16x16x32_f16(af, bf, acc[g], 0, 0, 0);
        }
        __syncthreads();
    }
    #pragma unroll
    for (int g = 0; g < 4; ++g) {
        #pragma unroll
        for (int reg = 0; reg < 4; ++reg) {
            int gr = row0 + w * 16 + quad * 4 + reg;
            int col = head * 64 + g * 16 + m;
            if (gr < nrows) {
                float v = acc[g][reg] + bias[col];
                v = v > 0.f ? v : (__expf(v) - 1.f);
                O[(size_t)gr * 256 + col] = (f16)v;
            }
        }
    }
}

// ---------------- layer-1 attention scores from xc directly ----------------
__global__ __launch_bounds__(256) void k_attx(const f16* __restrict__ xc,
                                              const float* __restrict__ a1ps,
                                              const float* __restrict__ a1pd,
                                              float* __restrict__ als,
                                              float* __restrict__ ald)
{
    int gid = blockIdx.x * 256 + threadIdx.x;
    int n = gid >> 6, lane = gid & 63;
    if (n >= NN) return;
    float xv = (float)xc[(size_t)n * 64 + lane];
    float ps[4], pd[4];
    #pragma unroll
    for (int h = 0; h < 4; ++h) {
        ps[h] = xv * a1ps[h * 64 + lane];
        pd[h] = xv * a1pd[h * 64 + lane];
    }
    #pragma unroll
    for (int off = 32; off > 0; off >>= 1) {
        #pragma unroll
        for (int h = 0; h < 4; ++h) {
            ps[h] += __shfl_xor(ps[h], off, 64);
            pd[h] += __shfl_xor(pd[h], off, 64);
        }
    }
    if (lane == 0) {
        #pragma unroll
        for (int h = 0; h < 4; ++h) {
            als[n * 4 + h] = ps[h];
            ald[n * 4 + h] = pd[h];
        }
    }
}

// ---------------- attention scores al_s/al_d [N,H] ----------------
template<int C, int D>
__global__ __launch_bounds__(256) void k_att(const f16* __restrict__ h,
                                             const float* __restrict__ asrc,
                                             const float* __restrict__ adst,
                                             float* __restrict__ als,
                                             float* __restrict__ ald)
{
    constexpr int V = C / 64;
    constexpr int H = C / D;
    constexpr int G = D / V;
    int gid = blockIdx.x * 256 + threadIdx.x;
    int n = gid >> 6;
    int lane = gid & 63;
    if (n >= NN) return;
    int c0 = lane * V;
    float ps = 0.f, pd = 0.f;
    #pragma unroll
    for (int j = 0; j < V; ++j) {
        float v = (float)h[(size_t)n * C + c0 + j];
        ps += v * asrc[c0 + j];
        pd += v * adst[c0 + j];
    }
    #pragma unroll
    for (int off = G / 2; off > 0; off >>= 1) {
        ps += __shfl_xor(ps, off, 64);
        pd += __shfl_xor(pd, off, 64);
    }
    if ((lane & (G - 1)) == 0) {
        int head = lane / G;
        als[n * H + head] = ps;
        ald[n * H + head] = pd;
    }
}

// -------- per-edge exp weights --------
template<int H>
__global__ __launch_bounds__(256) void k_ew(const int* __restrict__ csr,
                                            const int* __restrict__ dstarr,
                                            const float* __restrict__ als,
                                            const float* __restrict__ ald,
                                            float* __restrict__ earr)
{
    int i = blockIdx.x * 256 + threadIdx.x;
    if (i >= ETOT) return;
    int s = csr[i], d = dstarr[i];
    #pragma unroll
    for (int hh = 0; hh < H; ++hh) {
        float l = als[s * H + hh] + ald[d * H + hh];
        l = l > 0.f ? l : 0.2f * l;
        earr[(size_t)i * H + hh] = __expf(fminf(l, 80.f));
    }
}

// ------- layer-1 aggregate over xc (4-edge unroll) -------
__global__ __launch_bounds__(256) void k_aggx(const int* __restrict__ rowptr,
                                              const int* __restrict__ csr,
                                              const float* __restrict__ earr, // [i][4]
                                              const f16* __restrict__ xc,
                                              f16* __restrict__ xagg)
{
    int gid = blockIdx.x * 256 + threadIdx.x;
    int n = gid >> 6, lane = gid & 63;
    if (n >= NN) return;
    int r0 = rowptr[n], r1 = rowptr[n + 1];
    float a0 = 0.f, a1 = 0.f, a2 = 0.f, a3 = 0.f;
    float d0 = 0.f, d1 = 0.f, d2 = 0.f, d3 = 0.f;
    int i = r0;
    for (; i + 3 < r1; i += 4) {
        int s0 = csr[i], s1 = csr[i + 1], s2 = csr[i + 2], s3 = csr[i + 3];
        float4 e0 = *(const float4*)&earr[(size_t)i * 4];
        float4 e1 = *(const float4*)&earr[(size_t)(i + 1) * 4];
        float4 e2 = *(const float4*)&earr[(size_t)(i + 2) * 4];
        float4 e3 = *(const float4*)&earr[(size_t)(i + 3) * 4];
        float x0 = (float)xc[(size_t)s0 * 64 + lane];
        float x1 = (float)xc[(size_t)s1 * 64 + lane];
        float x2 = (float)xc[(size_t)s2 * 64 + lane];
        float x3 = (float)xc[(size_t)s3 * 64 + lane];
        a0 += e0.x * x0 + e1.x * x1 + e2.x * x2 + e3.x * x3;
        a1 += e0.y * x0 + e1.y * x1 + e2.y * x2 + e3.y * x3;
        a2 += e0.z * x0 + e1.z * x1 + e2.z * x2 + e3.z * x3;
        a3 += e0.w * x0 + e1.w * x1 + e2.w * x2 + e3.w * x3;
        d0 += e0.x + e1.x + e2.x + e3.x;
        d1 += e0.y + e1.y + e2.y + e3.y;
        d2 += e0.z + e1.z + e2.z + e3.z;
        d3 += e0.w + e1.w + e2.w + e3.w;
    }
    for (; i < r1; ++i) {
        int s0 = csr[i];
        float4 e0 = *(const float4*)&earr[(size_t)i * 4];
        float x0 = (float)xc[(size_t)s0 * 64 + lane];
        a0 += e0.x * x0; a1 += e0.y * x0; a2 += e0.z * x0; a3 += e0.w * x0;
        d0 += e0.x; d1 += e0.y; d2 += e0.z; d3 += e0.w;
    }
    size_t base = (size_t)n * 256 + lane;
    xagg[base]       = (f16)(a0 / d0);
    xagg[base + 64]  = (f16)(a1 / d1);
    xagg[base + 128] = (f16)(a2 / d2);
    xagg[base + 192] = (f16)(a3 / d3);
}

// ------- GAT aggregate (8-edge unroll): num=sum e*h, den=sum e; SPLIT waves/node -------
template<int C, int D, int SPLIT, bool ELU_>
__global__ __launch_bounds__(256) void k_agg2(const int* __restrict__ rowptr,
                                              const int* __restrict__ csr,
                                              const float* __restrict__ earr,
                                              const f16* __restrict__ h,
                                              const float* __restrict__ bias,
                                              f16* __restrict__ z)
{
    constexpr int H  = C / D;
    constexpr int CW = C / SPLIT;
    constexpr int V  = CW / 64;        // 2
    int gid = blockIdx.x * 256 + threadIdx.x;
    int wave = gid >> 6;
    int lane = gid & 63;
    int n     = (SPLIT == 2) ? (wave >> 1) : wave;
    int split = (SPLIT == 2) ? (wave & 1) : 0;
    if (n >= NN) return;
    int c0 = split * CW + lane * V;
    int head = c0 / D;
    int r0 = rowptr[n], r1 = rowptr[n + 1];
    float num0 = 0.f, num1 = 0.f, den = 0.f;
    int i = r0;
    for (; i + 7 < r1; i += 8) {
        int   s[8];
        float e[8];
        f16x2 hv[8];
        #pragma unroll
        for (int j = 0; j < 8; ++j) s[j] = csr[i + j];
        #pragma unroll
        for (int j = 0; j < 8; ++j) e[j] = earr[(size_t)(i + j) * H + head];
        #pragma unroll
        for (int j = 0; j < 8; ++j) hv[j] = *(const f16x2*)&h[(size_t)s[j] * C + c0];
        #pragma unroll
        for (int j = 0; j < 8; ++j) {
            num0 += e[j] * (float)hv[j][0];
            num1 += e[j] * (float)hv[j][1];
            den  += e[j];
        }
    }
    for (; i + 1 < r1; i += 2) {
        int s0 = csr[i], s1 = csr[i + 1];
        float e0 = earr[(size_t)i * H + head];
        float e1 = earr[(size_t)(i + 1) * H + head];
        f16x2 h0 = *(const f16x2*)&h[(size_t)s0 * C + c0];
        f16x2 h1 = *(const f16x2*)&h[(size_t)s1 * C + c0];
        num0 += e0 * (float)h0[0] + e1 * (float)h1[0];
        num1 += e0 * (float)h0[1] + e1 * (float)h1[1];
        den  += e0 + e1;
    }
    if (i < r1) {
        int s0 = csr[i];
        float e0 = earr[(size_t)i * H + head];
        f16x2 h0 = *(const f16x2*)&h[(size_t)s0 * C + c0];
        num0 += e0 * (float)h0[0];
        num1 += e0 * (float)h0[1];
        den  += e0;
    }
    float inv = 1.f / den;
    float v0 = num0 * inv + bias[c0];
    float v1 = num1 * inv + bias[c0 + 1];
    if (ELU_) {
        v0 = v0 > 0.f ? v0 : (__expf(v0) - 1.f);
        v1 = v1 > 0.f ? v1 : (__expf(v1) - 1.f);
    }
    f16x2 o = {(f16)v0, (f16)v1};
    *(f16x2*)&z[(size_t)n * C + c0] = o;
}

// ---------- decoder as tiled gather-GEMM: 64 edges x 64 cols per block ----------
__global__ __launch_bounds__(256) void k_decg(const f16* __restrict__ z3,
                                              const int* __restrict__ eli,
                                              const int* __restrict__ ntypes,
                                              const float* __restrict__ Wl1,
                                              const float* __restrict__ bl1,
                                              const float* __restrict__ Wl2,
                                              const float* __restrict__ bl2,
                                              const float* __restrict__ tb,
                                              float* __restrict__ out)
{
    __shared__ float As[16][64 + 4];
    __shared__ float Ws[16][64];
    __shared__ int sls[64], sld[64];
    const int t = threadIdx.x;
    const int e0 = blockIdx.x * 64;
    if (t < 64) {
        int e = e0 + t;
        sls[t] = (e < ELN) ? eli[e] : 0;
        sld[t] = (e < ELN) ? eli[ELN + e] : 0;
    }
    __syncthreads();
    const int tx = t & 15;
    const int ty = t >> 4;
    float acc[4][4] = {};
    for (int k0 = 0; k0 < 256; k0 += 16) {
        {
            int r  = t >> 2;
            int kk = (t & 3) * 4;
            int gk = k0 + kk;
            int node = (gk < 128) ? sls[r] : sld[r];
            f16x4 v = *(const f16x4*)&z3[(size_t)node * 128 + (gk & 127)];
            As[kk + 0][r] = (float)v[0];
            As[kk + 1][r] = (float)v[1];
            As[kk + 2][r] = (float)v[2];
            As[kk + 3][r] = (float)v[3];
        }
        {
            int row = t >> 4;
            int c4  = (t & 15) * 4;
            float4 v = *(const float4*)&Wl1[(size_t)(k0 + row) * 64 + c4];
            *(float4*)&Ws[row][c4] = v;
        }
        __syncthreads();
        #pragma unroll
        for (int kk = 0; kk < 16; ++kk) {
            float4 a = *(const float4*)&As[kk][ty * 4];
            float4 w = *(const float4*)&Ws[kk][tx * 4];
            float av[4] = {a.x, a.y, a.z, a.w};
            float wv[4] = {w.x, w.y, w.z, w.w};
            #pragma unroll
            for (int i = 0; i < 4; ++i)
                #pragma unroll
                for (int j = 0; j < 4; ++j) acc[i][j] += av[i] * wv[j];
        }
        __syncthreads();
    }
    float p[4];
    #pragma unroll
    for (int i = 0; i < 4; ++i) {
        float s = 0.f;
        #pragma unroll
        for (int j = 0; j < 4; ++j) {
            float hv = acc[i][j] + bl1[tx * 4 + j];
            hv = fmaxf(hv, 0.f);
            s += hv * Wl2[tx * 4 + j];
        }
        p[i] = s;
    }
    #pragma unroll
    for (int off = 1; off < 16; off <<= 1) {
        #pragma unroll
        for (int i = 0; i < 4; ++i) p[i] += __shfl_xor(p[i], off, 64);
    }
    if (tx == 0) {
        float b2v = bl2[0];
        #pragma unroll
        for (int i = 0; i < 4; ++i) {
            int r = ty * 4 + i;
            int e = e0 + r;
            if (e < ELN) {
                int ls = sls[r], ld = sld[r];
                out[e] = p[i] + b2v + tb[(size_t)ntypes[ls] * NT + ntypes[ld]];
            }
        }
    }
}

// ---------------- launch ----------------
extern "C" void kernel_launch(void* const* d_in, const int* in_sizes, int n_in,
                              void* d_out, int out_size, void* d_ws, size_t ws_size,
                              hipStream_t stream)
{
    const float* x   = (const float*)d_in[0];
    const int*   ei  = (const int*)d_in[1];
    const int*   eli = (const int*)d_in[2];
    const float* emb = (const float*)d_in[3];
    const float* W1  = (const float*)d_in[4];
    const float* as1 = (const float*)d_in[5];
    const float* ad1 = (const float*)d_in[6];
    const float* b1  = (const float*)d_in[7];
    const float* W2  = (const float*)d_in[8];
    const float* as2 = (const float*)d_in[9];
    const float* ad2 = (const float*)d_in[10];
    const float* b2  = (const float*)d_in[11];
    const float* W3  = (const float*)d_in[12];
    const float* as3 = (const float*)d_in[13];
    const float* ad3 = (const float*)d_in[14];
    const float* b3  = (const float*)d_in[15];
    const float* Wl1 = (const float*)d_in[16];
    const float* bl1 = (const float*)d_in[17];
    const float* Wl2 = (const float*)d_in[18];
    const float* bl2 = (const float*)d_in[19];
    const float* tb  = (const float*)d_in[20];
    float* out = (float*)d_out;

    char* ws = (char*)d_ws;
    size_t off = 0;
    auto alloc = [&](size_t bytes) { size_t o = off; off = (off + bytes + 255) & ~(size_t)255; return o; };
    int*   ntypes = (int*)  (ws + alloc((size_t)NN * 4));
    f16*   xc16   = (f16*)  (ws + alloc((size_t)NN * 64 * 2));
    int*   counts = (int*)  (ws + alloc((size_t)NN * 4));
    int*   cursor = (int*)  (ws + alloc((size_t)NN * 4));
    int*   rowptr = (int*)  (ws + alloc((size_t)(NN + 1) * 4));
    int*   csr    = (int*)  (ws + alloc((size_t)ETOT * 4));
    int*   dstarr = (int*)  (ws + alloc((size_t)ETOT * 4));
    int*   bsums  = (int*)  (ws + alloc((size_t)(SCAN_B + 1) * 4));
    int*   boff   = (int*)  (ws + alloc((size_t)(SCAN_B + 1) * 4));
    float* als    = (float*)(ws + alloc((size_t)NN * 4 * 4));
    float* ald    = (float*)(ws + alloc((size_t)NN * 4 * 4));
    float* earr   = (float*)(ws + alloc((size_t)ETOT * 4 * 4));
    f16*   h16    = (f16*)  (ws + alloc((size_t)NN * 256 * 2));   // also xagg
    f16*   z16    = (f16*)  (ws + alloc((size_t)NN * 256 * 2));
    f16*   Wt1    = (f16*)  (ws + alloc((size_t)4 * 64 * 64 * 2));
    f16*   Wt2    = (f16*)  (ws + alloc((size_t)256 * 256 * 2));
    f16*   Wt3    = (f16*)  (ws + alloc((size_t)128 * 256 * 2));
    float* a1ps   = (float*)(ws + alloc(256 * 4));
    float* a1pd   = (float*)(ws + alloc(256 * 4));

    hipMemsetAsync(counts, 0, (size_t)NN * 4, stream);

    const int gN   = (NN + 255) / 256;
    const int gE   = (ETOT + 255) / 256;
    const int RB   = (NN + 63) / 64;       // 782
    const int gW1  = (NN + 3) / 4;         // 1 wave/node
    const int gW2  = (2 * NN + 3) / 4;     // 2 waves/node

    k_prep<<<gN, 256, 0, stream>>>(x, emb, xc16, ntypes);
    k_cvtw1<<<(4 * 64 * 64 + 255) / 256, 256, 0, stream>>>(W1, Wt1);
    k_pre1<<<1, 256, 0, stream>>>(W1, as1, ad1, a1ps, a1pd);
    k_cvtw<256, 256, 256><<<(256 * 256 + 255) / 256, 256, 0, stream>>>(W2, Wt2);
    k_cvtw<256, 256, 128><<<(128 * 256 + 255) / 256, 256, 0, stream>>>(W3, Wt3);
    k_deg <<<gE, 256, 0, stream>>>(ei, counts);
    k_scan1<<<SCAN_B, 256, 0, stream>>>(counts, rowptr, bsums);
    k_scan2<<<1, 256, 0, stream>>>(bsums, boff);
    k_scan3<<<SCAN_B, 256, 0, stream>>>(rowptr, boff, cursor);
    k_fill<<<gE, 256, 0, stream>>>(ei, cursor, csr);
    k_dfill<<<gN, 256, 0, stream>>>(rowptr, dstarr);

    // Layer 1 (linearity-swapped)
    k_attx<<<gW1, 256, 0, stream>>>(xc16, a1ps, a1pd, als, ald);
    k_ew<4><<<gE, 256, 0, stream>>>(csr, dstarr, als, ald, earr);
    k_aggx<<<gW1, 256, 0, stream>>>(rowptr, csr, earr, xc16, h16 /*xagg*/);
    k_gemm1h<<<dim3(RB, 4), 256, 0, stream>>>(h16 /*xagg*/, Wt1, b1, z16, NN);

    // Layer 2
    k_gemmh<256, 256><<<dim3(RB, 4), 256, 0, stream>>>(z16, Wt2, h16, NN);
    k_att<256, 128><<<gW1, 256, 0, stream>>>(h16, as2, ad2, als, ald);
    k_ew<2><<<gE, 256, 0, stream>>>(csr, dstarr, als, ald, earr);
    k_agg2<256, 128, 2, true><<<gW2, 256, 0, stream>>>(rowptr, csr, earr, h16, b2, z16);

    // Layer 3
    k_gemmh<256, 128><<<dim3(RB, 2), 256, 0, stream>>>(z16, Wt3, h16, NN);
    k_att<128, 128><<<gW1, 256, 0, stream>>>(h16, as3, ad3, als, ald);
    k_ew<1><<<gE, 256, 0, stream>>>(csr, dstarr, als, ald, earr);
    k_agg2<128, 128, 1, false><<<gW1, 256, 0, stream>>>(rowptr, csr, earr, h16, b3, z16);

    // Decoder
    k_decg<<<(ELN + 63) / 64, 256, 0, stream>>>(z16, eli, ntypes, Wl1, bl1, Wl2, bl2, tb, out);
}

// Round 12
// 513.360 us; speedup vs baseline: 1.0375x; 1.0375x over previous
//
#include <hip/hip_runtime.h>
#include <hip/hip_bf16.h>

#define NN 50000
#define EE 800000
#define ELN 100000
#define ETOT (EE + NN)
#define NT 311
#define SCAN_B ((NN + 255) / 256)   // 196

typedef _Float16 f16;
typedef f16 f16x8 __attribute__((ext_vector_type(8)));
typedef f16 f16x4 __attribute__((ext_vector_type(4)));
typedef f16 f16x2 __attribute__((ext_vector_type(2)));
typedef float f32x4 __attribute__((ext_vector_type(4)));

// ---------------- prep: node types + x_comb [N,64] f16 (zero-padded 48->64) ----------------
__global__ __launch_bounds__(256) void k_prep(const float* __restrict__ x,
                                              const float* __restrict__ emb,
                                              f16* __restrict__ xc,
                                              int* __restrict__ ntypes)
{
    int n = blockIdx.x * 256 + threadIdx.x;
    if (n >= NN) return;
    int tpe = (int)x[(size_t)n * 33];
    tpe = tpe < 0 ? 0 : (tpe > NT - 1 ? NT - 1 : tpe);
    ntypes[n] = tpe;
    f16* o = xc + (size_t)n * 64;
    #pragma unroll
    for (int j = 0; j < 16; ++j) o[j] = (f16)emb[tpe * 16 + j];
    #pragma unroll
    for (int j = 0; j < 32; ++j) o[16 + j] = (f16)x[(size_t)n * 33 + 1 + j];
    #pragma unroll
    for (int j = 48; j < 64; ++j) o[j] = (f16)0.f;
}

// ---------------- weight convert+transpose: W[K][CN] f32 -> Wt[CN][KP] f16 ----------------
template<int K, int KP, int CN>
__global__ __launch_bounds__(256) void k_cvtw(const float* __restrict__ W,
                                              f16* __restrict__ Wt)
{
    int idx = blockIdx.x * 256 + threadIdx.x;
    if (idx >= CN * KP) return;
    int c = idx / KP;
    int k = idx - c * KP;
    Wt[idx] = (k < K) ? (f16)W[(size_t)k * CN + c] : (f16)0.f;
}

// ---- W1 per-head transpose ----
__global__ __launch_bounds__(256) void k_cvtw1(const float* __restrict__ W1,
                                               f16* __restrict__ Wt1)
{
    int idx = blockIdx.x * 256 + threadIdx.x;
    if (idx >= 4 * 64 * 64) return;
    int h = idx >> 12;
    int c = (idx >> 6) & 63;
    int k = idx & 63;
    Wt1[idx] = (k < 48) ? (f16)W1[(size_t)k * 256 + h * 64 + c] : (f16)0.f;
}

// ---- Wl1 transpose to f16: Wtl[c][k] = Wl1[k][c] ----
__global__ __launch_bounds__(256) void k_cvtwl(const float* __restrict__ Wl1,
                                               f16* __restrict__ Wtl)
{
    int idx = blockIdx.x * 256 + threadIdx.x;
    if (idx >= 64 * 256) return;
    int c = idx >> 8, k = idx & 255;
    Wtl[idx] = (f16)Wl1[(size_t)k * 64 + c];
}

// ---- fold a_src/a_dst through W1 ----
__global__ __launch_bounds__(256) void k_pre1(const float* __restrict__ W1,
                                              const float* __restrict__ as1,
                                              const float* __restrict__ ad1,
                                              float* __restrict__ a1ps,
                                              float* __restrict__ a1pd)
{
    int t = threadIdx.x;
    int h = t >> 6, k = t & 63;
    float ss = 0.f, sd = 0.f;
    if (k < 48) {
        for (int d = 0; d < 64; ++d) {
            float w = W1[(size_t)k * 256 + h * 64 + d];
            ss += w * as1[h * 64 + d];
            sd += w * ad1[h * 64 + d];
        }
    }
    a1ps[t] = ss;
    a1pd[t] = sd;
}

// ---------------- CSR build ----------------
__global__ __launch_bounds__(256) void k_deg(const int* __restrict__ ei,
                                             int* __restrict__ counts)
{
    int e = blockIdx.x * 256 + threadIdx.x;
    if (e >= ETOT) return;
    int dst = (e < EE) ? ei[EE + e] : (e - EE);
    atomicAdd(&counts[dst], 1);
}

// ---- 3-phase scan ----
__global__ __launch_bounds__(256) void k_scan1(const int* __restrict__ counts,
                                               int* __restrict__ rowptr,
                                               int* __restrict__ blocksums)
{
    __shared__ int s[256];
    int t = threadIdx.x;
    int i = blockIdx.x * 256 + t;
    int v = (i < NN) ? counts[i] : 0;
    s[t] = v;
    __syncthreads();
    #pragma unroll
    for (int off = 1; off < 256; off <<= 1) {
        int u = (t >= off) ? s[t - off] : 0;
        __syncthreads();
        s[t] += u;
        __syncthreads();
    }
    int incl = s[t];
    if (i < NN) rowptr[i] = incl - v;
    if (t == 255) blocksums[blockIdx.x] = incl;
}

__global__ __launch_bounds__(256) void k_scan2(int* __restrict__ blocksums,
                                               int* __restrict__ blockoff)
{
    __shared__ int s[256];
    int t = threadIdx.x;
    int v = (t < SCAN_B) ? blocksums[t] : 0;
    s[t] = v;
    __syncthreads();
    #pragma unroll
    for (int off = 1; off < 256; off <<= 1) {
        int u = (t >= off) ? s[t - off] : 0;
        __syncthreads();
        s[t] += u;
        __syncthreads();
    }
    if (t < SCAN_B) blockoff[t] = s[t] - v;
    if (t == SCAN_B - 1) blockoff[SCAN_B] = s[t];
}

__global__ __launch_bounds__(256) void k_scan3(int* __restrict__ rowptr,
                                               const int* __restrict__ blockoff,
                                               int* __restrict__ cursor)
{
    int i = blockIdx.x * 256 + threadIdx.x;
    if (i < NN) {
        int v = rowptr[i] + blockoff[blockIdx.x];
        rowptr[i] = v;
        cursor[i] = v;
    }
    if (i == 0) rowptr[NN] = blockoff[SCAN_B];
}

__global__ __launch_bounds__(256) void k_fill(const int* __restrict__ ei,
                                              int* __restrict__ cursor,
                                              int* __restrict__ csr_src)
{
    int e = blockIdx.x * 256 + threadIdx.x;
    if (e >= ETOT) return;
    int src, dst;
    if (e < EE) { src = ei[e]; dst = ei[EE + e]; }
    else        { src = e - EE; dst = e - EE; }
    int pos = atomicAdd(&cursor[dst], 1);
    csr_src[pos] = src;
}

__global__ __launch_bounds__(256) void k_dfill(const int* __restrict__ rowptr,
                                               int* __restrict__ dstarr)
{
    int n = blockIdx.x * 256 + threadIdx.x;
    if (n >= NN) return;
    int r0 = rowptr[n], r1 = rowptr[n + 1];
    for (int i = r0; i < r1; ++i) dstarr[i] = n;
}

// ------------- MFMA f16 GEMM -------------
template<int K, int CN>
__global__ __launch_bounds__(256) void k_gemmh(const f16* __restrict__ A,
                                               const f16* __restrict__ Wt,
                                               f16* __restrict__ O,
                                               int nrows)
{
    constexpr int LDA = 40;
    __shared__ f16 As[64 * LDA];
    __shared__ f16 Bs[64 * LDA];
    const int t = threadIdx.x;
    const int w = t >> 6;
    const int lane = t & 63;
    const int m = lane & 15;
    const int quad = lane >> 4;
    const int row0 = blockIdx.x * 64;
    const int col0 = blockIdx.y * 64;
    const int r_st = t >> 2;
    const int seg  = (t & 3) * 8;
    f32x4 acc[4] = {{0.f,0.f,0.f,0.f},{0.f,0.f,0.f,0.f},{0.f,0.f,0.f,0.f},{0.f,0.f,0.f,0.f}};
    for (int k0 = 0; k0 < K; k0 += 32) {
        int gr = row0 + r_st;
        f16x8 av = {0,0,0,0,0,0,0,0};
        if (gr < nrows) av = *(const f16x8*)&A[(size_t)gr * K + k0 + seg];
        *(f16x8*)&As[r_st * LDA + seg] = av;
        f16x8 bv = *(const f16x8*)&Wt[(size_t)(col0 + r_st) * K + k0 + seg];
        *(f16x8*)&Bs[r_st * LDA + seg] = bv;
        __syncthreads();
        f16x8 af = *(const f16x8*)&As[(w * 16 + m) * LDA + quad * 8];
        #pragma unroll
        for (int g = 0; g < 4; ++g) {
            f16x8 bf = *(const f16x8*)&Bs[(g * 16 + m) * LDA + quad * 8];
            acc[g] = __builtin_amdgcn_mfma_f32_16x16x32_f16(af, bf, acc[g], 0, 0, 0);
        }
        __syncthreads();
    }
    #pragma unroll
    for (int g = 0; g < 4; ++g) {
        #pragma unroll
        for (int reg = 0; reg < 4; ++reg) {
            int gr = row0 + w * 16 + quad * 4 + reg;
            int gc = col0 + g * 16 + m;
            if (gr < nrows) O[(size_t)gr * CN + gc] = (f16)acc[g][reg];
        }
    }
}

// ----- layer-1 per-head GEMM with fused bias+ELU -----
__global__ __launch_bounds__(256) void k_gemm1h(const f16* __restrict__ A,
                                                const f16* __restrict__ Wt1,
                                                const float* __restrict__ bias,
                                                f16* __restrict__ O,
                                                int nrows)
{
    constexpr int LDA = 40;
    __shared__ f16 As[64 * LDA];
    __shared__ f16 Bs[64 * LDA];
    const int t = threadIdx.x;
    const int w = t >> 6;
    const int lane = t & 63;
    const int m = lane & 15;
    const int quad = lane >> 4;
    const int row0 = blockIdx.x * 64;
    const int head = blockIdx.y;
    const int r_st = t >> 2;
    const int seg  = (t & 3) * 8;
    f32x4 acc[4] = {{0.f,0.f,0.f,0.f},{0.f,0.f,0.f,0.f},{0.f,0.f,0.f,0.f},{0.f,0.f,0.f,0.f}};
    for (int k0 = 0; k0 < 64; k0 += 32) {
        int gr = row0 + r_st;
        f16x8 av = {0,0,0,0,0,0,0,0};
        if (gr < nrows) av = *(const f16x8*)&A[(size_t)gr * 256 + head * 64 + k0 + seg];
        *(f16x8*)&As[r_st * LDA + seg] = av;
        f16x8 bv = *(const f16x8*)&Wt1[(size_t)head * 4096 + (size_t)r_st * 64 + k0 + seg];
        *(f16x8*)&Bs[r_st * LDA + seg] = bv;
        __syncthreads();
        f16x8 af = *(const f16x8*)&As[(w * 16 + m) * LDA + quad * 8];
        #pragma unroll
        for (int g = 0; g < 4; ++g) {
            f16x8 bf = *(const f16x8*)&Bs[(g * 16 + m) * LDA + quad * 8];
            acc[g] = __builtin_amdgcn_mfma_f32_16x16x32_f16(af, bf, acc[g], 0, 0, 0);
        }
        __syncthreads();
    }
    #pragma unroll
    for (int g = 0; g < 4; ++g) {
        #pragma unroll
        for (int reg = 0; reg < 4; ++reg) {
            int gr = row0 + w * 16 + quad * 4 + reg;
            int col = head * 64 + g * 16 + m;
            if (gr < nrows) {
                float v = acc[g][reg] + bias[col];
                v = v > 0.f ? v : (__expf(v) - 1.f);
                O[(size_t)gr * 256 + col] = (f16)v;
            }
        }
    }
}

// ---------------- layer-1 attention scores from xc directly ----------------
__global__ __launch_bounds__(256) void k_attx(const f16* __restrict__ xc,
                                              const float* __restrict__ a1ps,
                                              const float* __restrict__ a1pd,
                                              float* __restrict__ als,
                                              float* __restrict__ ald)
{
    int gid = blockIdx.x * 256 + threadIdx.x;
    int n = gid >> 6, lane = gid & 63;
    if (n >= NN) return;
    float xv = (float)xc[(size_t)n * 64 + lane];
    float ps[4], pd[4];
    #pragma unroll
    for (int h = 0; h < 4; ++h) {
        ps[h] = xv * a1ps[h * 64 + lane];
        pd[h] = xv * a1pd[h * 64 + lane];
    }
    #pragma unroll
    for (int off = 32; off > 0; off >>= 1) {
        #pragma unroll
        for (int h = 0; h < 4; ++h) {
            ps[h] += __shfl_xor(ps[h], off, 64);
            pd[h] += __shfl_xor(pd[h], off, 64);
        }
    }
    if (lane == 0) {
        #pragma unroll
        for (int h = 0; h < 4; ++h) {
            als[n * 4 + h] = ps[h];
            ald[n * 4 + h] = pd[h];
        }
    }
}

// ---------------- attention scores al_s/al_d [N,H] ----------------
template<int C, int D>
__global__ __launch_bounds__(256) void k_att(const f16* __restrict__ h,
                                             const float* __restrict__ asrc,
                                             const float* __restrict__ adst,
                                             float* __restrict__ als,
                                             float* __restrict__ ald)
{
    constexpr int V = C / 64;
    constexpr int H = C / D;
    constexpr int G = D / V;
    int gid = blockIdx.x * 256 + threadIdx.x;
    int n = gid >> 6;
    int lane = gid & 63;
    if (n >= NN) return;
    int c0 = lane * V;
    float ps = 0.f, pd = 0.f;
    #pragma unroll
    for (int j = 0; j < V; ++j) {
        float v = (float)h[(size_t)n * C + c0 + j];
        ps += v * asrc[c0 + j];
        pd += v * adst[c0 + j];
    }
    #pragma unroll
    for (int off = G / 2; off > 0; off >>= 1) {
        ps += __shfl_xor(ps, off, 64);
        pd += __shfl_xor(pd, off, 64);
    }
    if ((lane & (G - 1)) == 0) {
        int head = lane / G;
        als[n * H + head] = ps;
        ald[n * H + head] = pd;
    }
}

// -------- per-edge exp weights --------
template<int H>
__global__ __launch_bounds__(256) void k_ew(const int* __restrict__ csr,
                                            const int* __restrict__ dstarr,
                                            const float* __restrict__ als,
                                            const float* __restrict__ ald,
                                            float* __restrict__ earr)
{
    int i = blockIdx.x * 256 + threadIdx.x;
    if (i >= ETOT) return;
    int s = csr[i], d = dstarr[i];
    #pragma unroll
    for (int hh = 0; hh < H; ++hh) {
        float l = als[s * H + hh] + ald[d * H + hh];
        l = l > 0.f ? l : 0.2f * l;
        earr[(size_t)i * H + hh] = __expf(fminf(l, 80.f));
    }
}

// ------- layer-1 aggregate over xc (4-edge unroll) -------
__global__ __launch_bounds__(256) void k_aggx(const int* __restrict__ rowptr,
                                              const int* __restrict__ csr,
                                              const float* __restrict__ earr, // [i][4]
                                              const f16* __restrict__ xc,
                                              f16* __restrict__ xagg)
{
    int gid = blockIdx.x * 256 + threadIdx.x;
    int n = gid >> 6, lane = gid & 63;
    if (n >= NN) return;
    int r0 = rowptr[n], r1 = rowptr[n + 1];
    float a0 = 0.f, a1 = 0.f, a2 = 0.f, a3 = 0.f;
    float d0 = 0.f, d1 = 0.f, d2 = 0.f, d3 = 0.f;
    int i = r0;
    for (; i + 3 < r1; i += 4) {
        int s0 = csr[i], s1 = csr[i + 1], s2 = csr[i + 2], s3 = csr[i + 3];
        float4 e0 = *(const float4*)&earr[(size_t)i * 4];
        float4 e1 = *(const float4*)&earr[(size_t)(i + 1) * 4];
        float4 e2 = *(const float4*)&earr[(size_t)(i + 2) * 4];
        float4 e3 = *(const float4*)&earr[(size_t)(i + 3) * 4];
        float x0 = (float)xc[(size_t)s0 * 64 + lane];
        float x1 = (float)xc[(size_t)s1 * 64 + lane];
        float x2 = (float)xc[(size_t)s2 * 64 + lane];
        float x3 = (float)xc[(size_t)s3 * 64 + lane];
        a0 += e0.x * x0 + e1.x * x1 + e2.x * x2 + e3.x * x3;
        a1 += e0.y * x0 + e1.y * x1 + e2.y * x2 + e3.y * x3;
        a2 += e0.z * x0 + e1.z * x1 + e2.z * x2 + e3.z * x3;
        a3 += e0.w * x0 + e1.w * x1 + e2.w * x2 + e3.w * x3;
        d0 += e0.x + e1.x + e2.x + e3.x;
        d1 += e0.y + e1.y + e2.y + e3.y;
        d2 += e0.z + e1.z + e2.z + e3.z;
        d3 += e0.w + e1.w + e2.w + e3.w;
    }
    for (; i < r1; ++i) {
        int s0 = csr[i];
        float4 e0 = *(const float4*)&earr[(size_t)i * 4];
        float x0 = (float)xc[(size_t)s0 * 64 + lane];
        a0 += e0.x * x0; a1 += e0.y * x0; a2 += e0.z * x0; a3 += e0.w * x0;
        d0 += e0.x; d1 += e0.y; d2 += e0.z; d3 += e0.w;
    }
    size_t base = (size_t)n * 256 + lane;
    xagg[base]       = (f16)(a0 / d0);
    xagg[base + 64]  = (f16)(a1 / d1);
    xagg[base + 128] = (f16)(a2 / d2);
    xagg[base + 192] = (f16)(a3 / d3);
}

// ------- layer-2 aggregate, FULL ROW single wave per node (8-edge unroll) -------
// C=256, H=2: lane owns 4 channels; head = c0>>7 (lanes 0-31 head0, 32-63 head1)
__global__ __launch_bounds__(256) void k_agg2f(const int* __restrict__ rowptr,
                                               const int* __restrict__ csr,
                                               const float* __restrict__ earr, // [i][2]
                                               const f16* __restrict__ h,
                                               const float* __restrict__ bias,
                                               f16* __restrict__ z)
{
    int gid = blockIdx.x * 256 + threadIdx.x;
    int n = gid >> 6, lane = gid & 63;
    if (n >= NN) return;
    int c0 = lane * 4;
    int head = c0 >> 7;
    int r0 = rowptr[n], r1 = rowptr[n + 1];
    float a0 = 0.f, a1 = 0.f, a2 = 0.f, a3 = 0.f, den = 0.f;
    int i = r0;
    for (; i + 7 < r1; i += 8) {
        int   s[8];
        float e[8];
        f16x4 hv[8];
        #pragma unroll
        for (int j = 0; j < 8; ++j) s[j] = csr[i + j];
        #pragma unroll
        for (int j = 0; j < 8; ++j) e[j] = earr[(size_t)(i + j) * 2 + head];
        #pragma unroll
        for (int j = 0; j < 8; ++j) hv[j] = *(const f16x4*)&h[(size_t)s[j] * 256 + c0];
        #pragma unroll
        for (int j = 0; j < 8; ++j) {
            a0 += e[j] * (float)hv[j][0];
            a1 += e[j] * (float)hv[j][1];
            a2 += e[j] * (float)hv[j][2];
            a3 += e[j] * (float)hv[j][3];
            den += e[j];
        }
    }
    for (; i < r1; ++i) {
        int s0 = csr[i];
        float e0 = earr[(size_t)i * 2 + head];
        f16x4 hv = *(const f16x4*)&h[(size_t)s0 * 256 + c0];
        a0 += e0 * (float)hv[0];
        a1 += e0 * (float)hv[1];
        a2 += e0 * (float)hv[2];
        a3 += e0 * (float)hv[3];
        den += e0;
    }
    float inv = 1.f / den;
    float v0 = a0 * inv + bias[c0];
    float v1 = a1 * inv + bias[c0 + 1];
    float v2 = a2 * inv + bias[c0 + 2];
    float v3 = a3 * inv + bias[c0 + 3];
    v0 = v0 > 0.f ? v0 : (__expf(v0) - 1.f);
    v1 = v1 > 0.f ? v1 : (__expf(v1) - 1.f);
    v2 = v2 > 0.f ? v2 : (__expf(v2) - 1.f);
    v3 = v3 > 0.f ? v3 : (__expf(v3) - 1.f);
    f16x4 o = {(f16)v0, (f16)v1, (f16)v2, (f16)v3};
    *(f16x4*)&z[(size_t)n * 256 + c0] = o;
}

// ------- GAT aggregate (8-edge unroll), SPLIT template (used for layer 3) -------
template<int C, int D, int SPLIT, bool ELU_>
__global__ __launch_bounds__(256) void k_agg2(const int* __restrict__ rowptr,
                                              const int* __restrict__ csr,
                                              const float* __restrict__ earr,
                                              const f16* __restrict__ h,
                                              const float* __restrict__ bias,
                                              f16* __restrict__ z)
{
    constexpr int H  = C / D;
    constexpr int CW = C / SPLIT;
    constexpr int V  = CW / 64;        // 2
    int gid = blockIdx.x * 256 + threadIdx.x;
    int wave = gid >> 6;
    int lane = gid & 63;
    int n     = (SPLIT == 2) ? (wave >> 1) : wave;
    int split = (SPLIT == 2) ? (wave & 1) : 0;
    if (n >= NN) return;
    int c0 = split * CW + lane * V;
    int head = c0 / D;
    int r0 = rowptr[n], r1 = rowptr[n + 1];
    float num0 = 0.f, num1 = 0.f, den = 0.f;
    int i = r0;
    for (; i + 7 < r1; i += 8) {
        int   s[8];
        float e[8];
        f16x2 hv[8];
        #pragma unroll
        for (int j = 0; j < 8; ++j) s[j] = csr[i + j];
        #pragma unroll
        for (int j = 0; j < 8; ++j) e[j] = earr[(size_t)(i + j) * H + head];
        #pragma unroll
        for (int j = 0; j < 8; ++j) hv[j] = *(const f16x2*)&h[(size_t)s[j] * C + c0];
        #pragma unroll
        for (int j = 0; j < 8; ++j) {
            num0 += e[j] * (float)hv[j][0];
            num1 += e[j] * (float)hv[j][1];
            den  += e[j];
        }
    }
    for (; i < r1; ++i) {
        int s0 = csr[i];
        float e0 = earr[(size_t)i * H + head];
        f16x2 h0 = *(const f16x2*)&h[(size_t)s0 * C + c0];
        num0 += e0 * (float)h0[0];
        num1 += e0 * (float)h0[1];
        den  += e0;
    }
    float inv = 1.f / den;
    float v0 = num0 * inv + bias[c0];
    float v1 = num1 * inv + bias[c0 + 1];
    if (ELU_) {
        v0 = v0 > 0.f ? v0 : (__expf(v0) - 1.f);
        v1 = v1 > 0.f ? v1 : (__expf(v1) - 1.f);
    }
    f16x2 o = {(f16)v0, (f16)v1};
    *(f16x2*)&z[(size_t)n * C + c0] = o;
}

// ---------- MFMA decoder: 64 edges/block, ef[64][256]f16 @ Wtl[64][256]^T ----------
#define DLDA 264
__global__ __launch_bounds__(256) void k_decm(const f16* __restrict__ z3,
                                              const int* __restrict__ eli,
                                              const int* __restrict__ ntypes,
                                              const f16* __restrict__ Wtl,  // [64][256]
                                              const float* __restrict__ bl1,
                                              const float* __restrict__ Wl2,
                                              const float* __restrict__ bl2,
                                              const float* __restrict__ tb,
                                              float* __restrict__ out)
{
    __shared__ f16 As[64 * DLDA];
    __shared__ int sls[64], sld[64];
    const int t = threadIdx.x;
    const int e0 = blockIdx.x * 64;
    if (t < 64) {
        int e = e0 + t;
        sls[t] = (e < ELN) ? eli[e] : 0;
        sld[t] = (e < ELN) ? eli[ELN + e] : 0;
    }
    __syncthreads();
    // stage ef rows: thread t handles row r = t&63, col segment seg = t>>6 (64 cols)
    {
        int r = t & 63;
        int seg = t >> 6;
        int base = seg * 64;
        int node = (base < 128) ? sls[r] : sld[r];
        int zoff = base & 127;
        #pragma unroll
        for (int j = 0; j < 8; ++j) {
            f16x8 v = *(const f16x8*)&z3[(size_t)node * 128 + zoff + j * 8];
            *(f16x8*)&As[r * DLDA + base + j * 8] = v;
        }
    }
    __syncthreads();
    const int w = t >> 6;
    const int lane = t & 63;
    const int m = lane & 15;
    const int quad = lane >> 4;
    f32x4 acc[4] = {{0.f,0.f,0.f,0.f},{0.f,0.f,0.f,0.f},{0.f,0.f,0.f,0.f},{0.f,0.f,0.f,0.f}};
    for (int k0 = 0; k0 < 256; k0 += 32) {
        f16x8 af = *(const f16x8*)&As[(w * 16 + m) * DLDA + k0 + quad * 8];
        #pragma unroll
        for (int g = 0; g < 4; ++g) {
            f16x8 bf = *(const f16x8*)&Wtl[(size_t)(g * 16 + m) * 256 + k0 + quad * 8];
            acc[g] = __builtin_amdgcn_mfma_f32_16x16x32_f16(af, bf, acc[g], 0, 0, 0);
        }
    }
    // epilogue: s[reg] = sum over cols of relu(acc + bl1[col]) * Wl2[col]
    float s[4] = {0.f, 0.f, 0.f, 0.f};
    #pragma unroll
    for (int g = 0; g < 4; ++g) {
        int col = g * 16 + m;
        float b = bl1[col], wv = Wl2[col];
        #pragma unroll
        for (int reg = 0; reg < 4; ++reg) {
            float hv = fmaxf(acc[g][reg] + b, 0.f);
            s[reg] += hv * wv;
        }
    }
    #pragma unroll
    for (int off = 1; off < 16; off <<= 1) {
        #pragma unroll
        for (int reg = 0; reg < 4; ++reg) s[reg] += __shfl_xor(s[reg], off, 64);
    }
    if (m == 0) {
        float b2v = bl2[0];
        #pragma unroll
        for (int reg = 0; reg < 4; ++reg) {
            int r = w * 16 + quad * 4 + reg;
            int e = e0 + r;
            if (e < ELN) {
                out[e] = s[reg] + b2v +
                         tb[(size_t)ntypes[sls[r]] * NT + ntypes[sld[r]]];
            }
        }
    }
}

// ---------------- launch ----------------
extern "C" void kernel_launch(void* const* d_in, const int* in_sizes, int n_in,
                              void* d_out, int out_size, void* d_ws, size_t ws_size,
                              hipStream_t stream)
{
    const float* x   = (const float*)d_in[0];
    const int*   ei  = (const int*)d_in[1];
    const int*   eli = (const int*)d_in[2];
    const float* emb = (const float*)d_in[3];
    const float* W1  = (const float*)d_in[4];
    const float* as1 = (const float*)d_in[5];
    const float* ad1 = (const float*)d_in[6];
    const float* b1  = (const float*)d_in[7];
    const float* W2  = (const float*)d_in[8];
    const float* as2 = (const float*)d_in[9];
    const float* ad2 = (const float*)d_in[10];
    const float* b2  = (const float*)d_in[11];
    const float* W3  = (const float*)d_in[12];
    const float* as3 = (const float*)d_in[13];
    const float* ad3 = (const float*)d_in[14];
    const float* b3  = (const float*)d_in[15];
    const float* Wl1 = (const float*)d_in[16];
    const float* bl1 = (const float*)d_in[17];
    const float* Wl2 = (const float*)d_in[18];
    const float* bl2 = (const float*)d_in[19];
    const float* tb  = (const float*)d_in[20];
    float* out = (float*)d_out;

    char* ws = (char*)d_ws;
    size_t off = 0;
    auto alloc = [&](size_t bytes) { size_t o = off; off = (off + bytes + 255) & ~(size_t)255; return o; };
    int*   ntypes = (int*)  (ws + alloc((size_t)NN * 4));
    f16*   xc16   = (f16*)  (ws + alloc((size_t)NN * 64 * 2));
    int*   counts = (int*)  (ws + alloc((size_t)NN * 4));
    int*   cursor = (int*)  (ws + alloc((size_t)NN * 4));
    int*   rowptr = (int*)  (ws + alloc((size_t)(NN + 1) * 4));
    int*   csr    = (int*)  (ws + alloc((size_t)ETOT * 4));
    int*   dstarr = (int*)  (ws + alloc((size_t)ETOT * 4));
    int*   bsums  = (int*)  (ws + alloc((size_t)(SCAN_B + 1) * 4));
    int*   boff   = (int*)  (ws + alloc((size_t)(SCAN_B + 1) * 4));
    float* als    = (float*)(ws + alloc((size_t)NN * 4 * 4));
    float* ald    = (float*)(ws + alloc((size_t)NN * 4 * 4));
    float* earr   = (float*)(ws + alloc((size_t)ETOT * 4 * 4));
    f16*   h16    = (f16*)  (ws + alloc((size_t)NN * 256 * 2));   // also xagg
    f16*   z16    = (f16*)  (ws + alloc((size_t)NN * 256 * 2));
    f16*   Wt1    = (f16*)  (ws + alloc((size_t)4 * 64 * 64 * 2));
    f16*   Wt2    = (f16*)  (ws + alloc((size_t)256 * 256 * 2));
    f16*   Wt3    = (f16*)  (ws + alloc((size_t)128 * 256 * 2));
    f16*   Wtl    = (f16*)  (ws + alloc((size_t)64 * 256 * 2));
    float* a1ps   = (float*)(ws + alloc(256 * 4));
    float* a1pd   = (float*)(ws + alloc(256 * 4));

    hipMemsetAsync(counts, 0, (size_t)NN * 4, stream);

    const int gN   = (NN + 255) / 256;
    const int gE   = (ETOT + 255) / 256;
    const int RB   = (NN + 63) / 64;       // 782
    const int gW1  = (NN + 3) / 4;         // 1 wave/node

    k_prep<<<gN, 256, 0, stream>>>(x, emb, xc16, ntypes);
    k_cvtw1<<<(4 * 64 * 64 + 255) / 256, 256, 0, stream>>>(W1, Wt1);
    k_pre1<<<1, 256, 0, stream>>>(W1, as1, ad1, a1ps, a1pd);
    k_cvtw<256, 256, 256><<<(256 * 256 + 255) / 256, 256, 0, stream>>>(W2, Wt2);
    k_cvtw<256, 256, 128><<<(128 * 256 + 255) / 256, 256, 0, stream>>>(W3, Wt3);
    k_cvtwl<<<(64 * 256 + 255) / 256, 256, 0, stream>>>(Wl1, Wtl);
    k_deg <<<gE, 256, 0, stream>>>(ei, counts);
    k_scan1<<<SCAN_B, 256, 0, stream>>>(counts, rowptr, bsums);
    k_scan2<<<1, 256, 0, stream>>>(bsums, boff);
    k_scan3<<<SCAN_B, 256, 0, stream>>>(rowptr, boff, cursor);
    k_fill<<<gE, 256, 0, stream>>>(ei, cursor, csr);
    k_dfill<<<gN, 256, 0, stream>>>(rowptr, dstarr);

    // Layer 1 (linearity-swapped)
    k_attx<<<gW1, 256, 0, stream>>>(xc16, a1ps, a1pd, als, ald);
    k_ew<4><<<gE, 256, 0, stream>>>(csr, dstarr, als, ald, earr);
    k_aggx<<<gW1, 256, 0, stream>>>(rowptr, csr, earr, xc16, h16 /*xagg*/);
    k_gemm1h<<<dim3(RB, 4), 256, 0, stream>>>(h16 /*xagg*/, Wt1, b1, z16, NN);

    // Layer 2
    k_gemmh<256, 256><<<dim3(RB, 4), 256, 0, stream>>>(z16, Wt2, h16, NN);
    k_att<256, 128><<<gW1, 256, 0, stream>>>(h16, as2, ad2, als, ald);
    k_ew<2><<<gE, 256, 0, stream>>>(csr, dstarr, als, ald, earr);
    k_agg2f<<<gW1, 256, 0, stream>>>(rowptr, csr, earr, h16, b2, z16);

    // Layer 3
    k_gemmh<256, 128><<<dim3(RB, 2), 256, 0, stream>>>(z16, Wt3, h16, NN);
    k_att<128, 128><<<gW1, 256, 0, stream>>>(h16, as3, ad3, als, ald);
    k_ew<1><<<gE, 256, 0, stream>>>(csr, dstarr, als, ald, earr);
    k_agg2<128, 128, 1, false><<<gW1, 256, 0, stream>>>(rowptr, csr, earr, h16, b3, z16);

    // Decoder (MFMA)
    k_decm<<<(ELN + 63) / 64, 256, 0, stream>>>(z16, eli, ntypes, Wtl, bl1, Wl2, bl2, tb, out);
}